// Round 3
// baseline (775.058 us; speedup 1.0000x reference)
//
#include <hip/hip_runtime.h>
#include <math.h>

#define D_MODEL 1024
#define TT 4096
#define NB 4
#define NH 16
#define NCH 16

typedef __attribute__((ext_vector_type(8))) short s8v;
typedef __attribute__((ext_vector_type(4))) float f4v;

// ---- workspace layout (bytes); touched ~100 MB at P=2048 ----
#define OFF_STATS ((size_t)0)
#define OFF_G     ((size_t)(1 << 20))
#define OFF_MM    (OFF_G + (size_t)(256 << 10))
#define OFF_CV    (OFF_MM + (size_t)(256 << 10))
#define OFF_FT    ((size_t)(2 << 20))
#define OFF_AFF   (OFF_FT + (size_t)(512 << 10))
#define OFF_WKVH  ((size_t)(3 << 20))
#define OFF_WKVL  ((size_t)(6 << 20))
#define OFF_WQH   ((size_t)(9 << 20))
#define OFF_WQL   ((size_t)(10 << 20))
#define OFF_ETH   ((size_t)(11 << 20))
#define OFF_ETL   ((size_t)(15 << 20))
#define OFF_Y1F   ((size_t)(20 << 20))
#define OFF_Y1H   ((size_t)(52 << 20))
#define OFF_Y2    ((size_t)(68 << 20))

#define GLOAD(g, l) __builtin_amdgcn_global_load_lds(                         \
    (const __attribute__((address_space(1))) unsigned int*)(const void*)(g),  \
    (__attribute__((address_space(3))) unsigned int*)(void*)(l), 16, 0, 0)

__device__ __forceinline__ unsigned short bf16_rne(float x) {
  unsigned u = __float_as_uint(x);
  return (unsigned short)((u + 0x7fffu + ((u >> 16) & 1u)) >> 16);
}
__device__ __forceinline__ void split_bf16(float x, unsigned short& h, unsigned short& l) {
  unsigned u = __float_as_uint(x);
  unsigned r = (u + 0x7fffu + ((u >> 16) & 1u)) & 0xffff0000u;
  h = (unsigned short)(r >> 16);
  float res = x - __uint_as_float(r);
  l = bf16_rne(res);
}

// ---------------- LayerNorm statistics: one block per row ----------------
__global__ __launch_bounds__(256) void ln_stats_k(const float* __restrict__ X,
                                                  float* __restrict__ stats) {
  int r = blockIdx.x;
  const float4 v = ((const float4*)(X + (size_t)r * D_MODEL))[threadIdx.x];
  float s  = v.x + v.y + v.z + v.w;
  float ss = v.x * v.x + v.y * v.y + v.z * v.z + v.w * v.w;
#pragma unroll
  for (int off = 32; off > 0; off >>= 1) {
    s  += __shfl_down(s, off, 64);
    ss += __shfl_down(ss, off, 64);
  }
  __shared__ float as_[4], bs_[4];
  int w = threadIdx.x >> 6, lane = threadIdx.x & 63;
  if (lane == 0) { as_[w] = s; bs_[w] = ss; }
  __syncthreads();
  if (threadIdx.x == 0) {
    float S  = as_[0] + as_[1] + as_[2] + as_[3];
    float SS = bs_[0] + bs_[1] + bs_[2] + bs_[3];
    float mu  = S * (1.0f / D_MODEL);
    float var = SS * (1.0f / D_MODEL) - mu * mu;
    stats[2 * (size_t)r]     = mu;
    stats[2 * (size_t)r + 1] = 1.0f / sqrtf(var + 1e-5f);
  }
}

// ------- prep: transpose (diag(g)·W)[K][N] -> [nofs+n][K] bf16 hi/lo -------
__global__ __launch_bounds__(256) void prep_w_k(const float* __restrict__ W, int N, int nofs,
                                                const float* __restrict__ g,
                                                unsigned short* __restrict__ Thi,
                                                unsigned short* __restrict__ Tlo) {
  __shared__ float tileT[32 * 33];
  const int n0 = blockIdx.x * 32, k0 = blockIdx.y * 32;
  const int tid = threadIdx.x;
  {
    int k_l = tid >> 3, n4 = (tid & 7) << 2;
    float gk = g[k0 + k_l];
    float4 v = *(const float4*)&W[(size_t)(k0 + k_l) * N + n0 + n4];
    tileT[(n4 + 0) * 33 + k_l] = v.x * gk;
    tileT[(n4 + 1) * 33 + k_l] = v.y * gk;
    tileT[(n4 + 2) * 33 + k_l] = v.z * gk;
    tileT[(n4 + 3) * 33 + k_l] = v.w * gk;
  }
  __syncthreads();
  {
    int n_l = tid >> 3, k4 = (tid & 7) << 2;
    unsigned short h[4], l[4];
#pragma unroll
    for (int i = 0; i < 4; i++) split_bf16(tileT[n_l * 33 + k4 + i], h[i], l[i]);
    *(ushort4*)&Thi[(size_t)(nofs + n0 + n_l) * 1024 + k0 + k4] = make_ushort4(h[0], h[1], h[2], h[3]);
    *(ushort4*)&Tlo[(size_t)(nofs + n0 + n_l) * 1024 + k0 + k4] = make_ushort4(l[0], l[1], l[2], l[3]);
  }
}

// ------- affine vectors: gW[n] = sum_k g[k]W[k,n], bW[n] = sum_k b[k]W[k,n] -------
__global__ __launch_bounds__(256) void affine_k(const float* __restrict__ W, int N,
                                                const float* __restrict__ g,
                                                const float* __restrict__ bv,
                                                float* __restrict__ outG,
                                                float* __restrict__ outB) {
  int n = blockIdx.x * 256 + threadIdx.x;
  if (n >= N) return;
  float sgv = 0.f, sbv = 0.f;
  for (int k = 0; k < 1024; k++) {
    float w = W[(size_t)k * N + n];
    sgv += g[k] * w;
    sbv += bv[k] * w;
  }
  outG[n] = sgv;
  outB[n] = sbv;
}

// ------- projection GEMM: raw-X split-bf16 (3 products), LN folded to epilogue -------
// mode 0: rows t<P (compact), W = [WgK|WgV] N=1536; n<512 -> keys (Y1F,Y1H), n>=512 -> values (Y2)
// mode 1: rows t>=P (compact), W = WgQ N=512 -> queries (Y1H)
__global__ __launch_bounds__(256) void gemm_proj_k(
    const float* __restrict__ X, const float* __restrict__ stats,
    const unsigned short* __restrict__ WTh, const unsigned short* __restrict__ WTl,
    const float* __restrict__ affG, const float* __restrict__ affB,
    const int* __restrict__ pref, int mode,
    float* __restrict__ Y1F, unsigned short* __restrict__ Y1H,
    float* __restrict__ Y2) {
  int P = pref[0]; P = P < 1 ? 1 : (P > TT - 1 ? TT - 1 : P);
  const int limit = (mode == 0) ? NB * P : NB * (TT - P);
  const int m0 = blockIdx.y * 128;
  if (m0 >= limit) return;
  const int n0 = blockIdx.x * 128;
  __shared__ __align__(16) unsigned short Ah[128 * 40], Al[128 * 40];
  __shared__ __align__(16) unsigned short Bh[128 * 32], Bl[128 * 32];
  __shared__ int rowoff[128];
  __shared__ float mus[128], rss[128], aGs[128], aBs[128];
  const int tid = threadIdx.x;
  if (tid < 128) {
    int gm = m0 + tid;
    int grow = 0;
    if (gm < limit) {
      if (mode == 0) {
        unsigned bq = (unsigned)gm / (unsigned)P;
        grow = bq * TT + (gm - bq * P);
      } else {
        unsigned q = (unsigned)(TT - P);
        unsigned bq = (unsigned)gm / q;
        grow = bq * TT + P + (gm - bq * q);
      }
    }
    rowoff[tid] = grow;
    mus[tid] = stats[2 * (size_t)grow];
    rss[tid] = stats[2 * (size_t)grow + 1];
    aGs[tid] = affG[n0 + tid];
    aBs[tid] = affB[n0 + tid];
  }
  const int lane = tid & 63;
  const int w = tid >> 6;
  const int wm = (w >> 1) * 64, wn = (w & 1) * 64;
  const int lm = lane & 15, lq = lane >> 4;
  f4v acc[4][4];
#pragma unroll
  for (int i = 0; i < 4; i++)
#pragma unroll
    for (int j = 0; j < 4; j++) acc[i][j] = (f4v){0.f, 0.f, 0.f, 0.f};

  for (int kt = 0; kt < 1024; kt += 32) {
    __syncthreads();
    // B: async global->LDS, XOR-swizzled chunks (unpadded stride 32)
#pragma unroll
    for (int i = 0; i < 2; i++) {
      int sbase = w * 128 + i * 64;
      int idx = sbase + lane;
      int r = idx >> 2, cl = idx & 3;
      int cg = cl ^ ((r + (r >> 2)) & 3);
      size_t go = (size_t)(n0 + r) * 1024 + kt + cg * 8;
      GLOAD(&WTh[go], &Bh[sbase * 8]);
      GLOAD(&WTl[go], &Bl[sbase * 8]);
    }
    // A: fp32 load + split-bf16 into padded LDS (stride 40)
#pragma unroll
    for (int q = 0; q < 2; q++) {
      int c = tid * 2 + q;
      int m = c >> 2, k8 = (c & 3) << 3;
      const float* src = &X[(size_t)rowoff[m] * 1024 + kt + k8];
      float4 v0 = *(const float4*)&src[0];
      float4 v1 = *(const float4*)&src[4];
      float vv[8] = {v0.x, v0.y, v0.z, v0.w, v1.x, v1.y, v1.z, v1.w};
      unsigned short hh[8], ll[8];
#pragma unroll
      for (int i = 0; i < 8; i++) split_bf16(vv[i], hh[i], ll[i]);
      *(ushort4*)&Ah[m * 40 + k8]     = make_ushort4(hh[0], hh[1], hh[2], hh[3]);
      *(ushort4*)&Ah[m * 40 + k8 + 4] = make_ushort4(hh[4], hh[5], hh[6], hh[7]);
      *(ushort4*)&Al[m * 40 + k8]     = make_ushort4(ll[0], ll[1], ll[2], ll[3]);
      *(ushort4*)&Al[m * 40 + k8 + 4] = make_ushort4(ll[4], ll[5], ll[6], ll[7]);
    }
    __syncthreads();
    s8v ah[4], al[4], bh4[4], bl4[4];
#pragma unroll
    for (int i = 0; i < 4; i++) {
      int ar = (wm + i * 16 + lm) * 40 + lq * 8;
      ah[i] = *(const s8v*)&Ah[ar];
      al[i] = *(const s8v*)&Al[ar];
      int brr = wn + i * 16 + lm;
      int bch = lq ^ ((brr + (brr >> 2)) & 3);
      int br = brr * 32 + bch * 8;
      bh4[i] = *(const s8v*)&Bh[br];
      bl4[i] = *(const s8v*)&Bl[br];
    }
#pragma unroll
    for (int mi = 0; mi < 4; mi++)
#pragma unroll
      for (int ni = 0; ni < 4; ni++) {
        acc[mi][ni] = __builtin_amdgcn_mfma_f32_16x16x32_bf16(ah[mi], bh4[ni], acc[mi][ni], 0, 0, 0);
        acc[mi][ni] = __builtin_amdgcn_mfma_f32_16x16x32_bf16(ah[mi], bl4[ni], acc[mi][ni], 0, 0, 0);
        acc[mi][ni] = __builtin_amdgcn_mfma_f32_16x16x32_bf16(al[mi], bh4[ni], acc[mi][ni], 0, 0, 0);
      }
  }
#pragma unroll
  for (int mi = 0; mi < 4; mi++) {
#pragma unroll
    for (int r = 0; r < 4; r++) {
      int ml = wm + mi * 16 + lq * 4 + r;
      int gm = m0 + ml;
      if (gm >= limit) continue;
      int grow = rowoff[ml];
      float mu = mus[ml], rs = rss[ml];
#pragma unroll
      for (int ni = 0; ni < 4; ni++) {
        int nl = wn + ni * 16 + lm;
        int n = n0 + nl;
        float v = rs * acc[mi][ni][r] + aBs[nl] - rs * mu * aGs[nl];
        if (mode == 0) {
          if (n0 < 512) {
            Y1F[(size_t)grow * 512 + n] = v;
            Y1H[(size_t)grow * 512 + n] = bf16_rne(v);
          } else {
            Y2[(size_t)gm * 1024 + (n - 512)] = v;
          }
        } else {
          Y1H[(size_t)grow * 512 + n] = bf16_rne(v);
        }
      }
    }
  }
}

// ------------- G, M, C_v Gram reductions (atomic accumulate) -------------
__global__ __launch_bounds__(256) void build_gmc_k(
    const float* __restrict__ Y1, const float* __restrict__ Y2,
    const int* __restrict__ pref,
    float* __restrict__ G, float* __restrict__ Mm, float* __restrict__ Cv) {
  int P = pref[0]; P = P < 1 ? 1 : (P > TT - 1 ? TT - 1 : P);
  const int bh = blockIdx.y;
  const int b = bh >> 4, h = bh & 15;
  const int tid = threadIdx.x;
  const int chunk = (P + NCH - 1) / NCH;
  const int tb = blockIdx.x * chunk;
  const int te = min(tb + chunk, P);
  if (tb >= te) return;
  __shared__ float kt[129 * 32];
  __shared__ float vt[128 * 64];
  float aG[4] = {}, aM[4] = {}, aC[8] = {};
  const int ii = tid >> 3, j4 = (tid & 7) << 2;
  const int dd = tid >> 2, j8 = (tid & 3) << 3;
  for (int t0 = tb; t0 < te; t0 += 128) {
    const int len = min(128, te - t0);
    __syncthreads();
    for (int e = tid; e < (len + 1) * 8; e += 256) {
      int row = e >> 3, jj = (e & 7) << 2;
      int t = t0 - 1 + row;
      float4 v = make_float4(0.f, 0.f, 0.f, 0.f);
      if (t >= 0) v = *(const float4*)&Y1[((size_t)b * TT + t) * 512 + h * 32 + jj];
      *(float4*)&kt[row * 32 + jj] = v;
    }
    for (int e = tid; e < len * 16; e += 256) {
      int row = e >> 4, dj = (e & 15) << 2;
      int t = t0 + row;
      *(float4*)&vt[row * 64 + dj] =
          *(const float4*)&Y2[((size_t)b * P + t) * 1024 + h * 64 + dj];
    }
    __syncthreads();
    for (int s = 0; s < len; s++) {
      float ki  = kt[(s + 1) * 32 + ii];
      float4 kj = *(const float4*)&kt[(s + 1) * 32 + j4];
      float4 km = *(const float4*)&kt[s * 32 + j4];
      aG[0] += ki * kj.x; aG[1] += ki * kj.y; aG[2] += ki * kj.z; aG[3] += ki * kj.w;
      aM[0] += ki * km.x; aM[1] += ki * km.y; aM[2] += ki * km.z; aM[3] += ki * km.w;
      float vd  = vt[s * 64 + dd];
      float4 ka = *(const float4*)&kt[(s + 1) * 32 + j8];
      float4 kb = *(const float4*)&kt[(s + 1) * 32 + j8 + 4];
      aC[0] += vd * ka.x; aC[1] += vd * ka.y; aC[2] += vd * ka.z; aC[3] += vd * ka.w;
      aC[4] += vd * kb.x; aC[5] += vd * kb.y; aC[6] += vd * kb.z; aC[7] += vd * kb.w;
    }
  }
  float* Gd = &G[(size_t)bh * 1024 + ii * 32 + j4];
  atomicAdd(&Gd[0], aG[0]); atomicAdd(&Gd[1], aG[1]);
  atomicAdd(&Gd[2], aG[2]); atomicAdd(&Gd[3], aG[3]);
  float* Md = &Mm[(size_t)bh * 1024 + ii * 32 + j4];
  atomicAdd(&Md[0], aM[0]); atomicAdd(&Md[1], aM[1]);
  atomicAdd(&Md[2], aM[2]); atomicAdd(&Md[3], aM[3]);
  float* Cd = &Cv[(size_t)bh * 2048 + dd * 32 + j8];
#pragma unroll
  for (int q = 0; q < 8; q++) atomicAdd(&Cd[q], aC[q]);
}

// ------- per-(b,h) operator: chol, G^{-1}, A_w, sigma, F = Cv*Gi*(s*M*Gi)^4 -------
__global__ __launch_bounds__(256) void solve_op_k(
    const float* __restrict__ G, const float* __restrict__ Mm,
    const float* __restrict__ Cv, const float* __restrict__ lridge,
    const float* __restrict__ lgamma, float* __restrict__ Ft) {
  __shared__ float Gs[32 * 33];
  __shared__ float Ms[32 * 32];
  __shared__ float Gi[32 * 32];
  __shared__ float W1[32 * 33];
  __shared__ float Aw[32 * 33];
  __shared__ float Nn[32 * 32];
  __shared__ float N2[32 * 32];
  __shared__ float T1[32 * 32];
  __shared__ float Cs[64 * 32];
  __shared__ float red[256];
  __shared__ float vv[32], uu[32];
  const int bh = blockIdx.x;
  const int tid = threadIdx.x;
  const float ridge = expf(lridge[0]);

  for (int e = tid; e < 1024; e += 256) {
    int i = e >> 5, j = e & 31;
    float g = G[(size_t)bh * 1024 + e];
    if (i == j) g += ridge;
    Gs[i * 33 + j] = g;
    Ms[e] = Mm[(size_t)bh * 1024 + e];
  }
  for (int e = tid; e < 2048; e += 256) Cs[e] = Cv[(size_t)bh * 2048 + e];
  __syncthreads();

  for (int j = 0; j < 32; j++) {
    float d = Gs[j * 33 + j];
    __syncthreads();
    float inv = 1.0f / sqrtf(d);
    if (tid >= j && tid < 32) Gs[tid * 33 + j] *= inv;
    __syncthreads();
    int w = 31 - j;
    for (int e = tid; e < w * w; e += 256) {
      int i = j + 1 + e / w, k = j + 1 + e % w;
      Gs[i * 33 + k] -= Gs[i * 33 + j] * Gs[k * 33 + j];
    }
    __syncthreads();
  }

  if (tid < 32) {
    const int c = tid;
    for (int i = 0; i < 32; i++) W1[i * 33 + c] = (i == c) ? 1.0f : 0.0f;
    for (int i = 0; i < 32; i++) {
      float s = W1[i * 33 + c];
      for (int j = 0; j < i; j++) s -= Gs[i * 33 + j] * W1[j * 33 + c];
      W1[i * 33 + c] = s / Gs[i * 33 + i];
    }
    for (int i = 31; i >= 0; i--) {
      float s = W1[i * 33 + c];
      for (int j = i + 1; j < 32; j++) s -= Gs[j * 33 + i] * W1[j * 33 + c];
      W1[i * 33 + c] = s / Gs[i * 33 + i];
    }
    for (int i = 0; i < 32; i++) Gi[i * 32 + c] = W1[i * 33 + c];
  }
  __syncthreads();
  if (tid < 32) {
    const int c = tid;
    for (int i = 0; i < 32; i++) {
      float s = Ms[i * 32 + c];
      for (int j = 0; j < i; j++) s -= Gs[i * 33 + j] * W1[j * 33 + c];
      W1[i * 33 + c] = s / Gs[i * 33 + i];
    }
  }
  __syncthreads();
  if (tid < 32) {
    const int c = tid;
    for (int i = 0; i < 32; i++) {
      float s = W1[c * 33 + i];
      for (int j = 0; j < i; j++) s -= Gs[i * 33 + j] * Aw[j * 33 + c];
      Aw[i * 33 + c] = s / Gs[i * 33 + i];
    }
  }
  __syncthreads();

  float s0 = 0.0f;
  for (int e = tid; e < 1024; e += 256) {
    float a = Aw[(e >> 5) * 33 + (e & 31)];
    s0 += a * a;
  }
  red[tid] = s0;
  __syncthreads();
  for (int off = 128; off > 0; off >>= 1) {
    if (tid < off) red[tid] += red[tid + off];
    __syncthreads();
  }
  float frob2 = red[0];
  float sigma;
  if (frob2 <= 1.0f) {
    sigma = sqrtf(frob2);
  } else {
    if (tid < 32) vv[tid] = 1.0f + 0.001f * (float)tid;
    __syncthreads();
    for (int it = 0; it < 64; it++) {
      if (tid < 32) {
        float s = 0;
        for (int j = 0; j < 32; j++) s += Aw[tid * 33 + j] * vv[j];
        uu[tid] = s;
      }
      __syncthreads();
      if (tid == 0) {
        float n = 0;
        for (int j = 0; j < 32; j++) n += uu[j] * uu[j];
        red[0] = sqrtf(n);
      }
      __syncthreads();
      float nu = fmaxf(red[0], 1e-30f);
      if (tid < 32) uu[tid] /= nu;
      __syncthreads();
      if (tid < 32) {
        float s = 0;
        for (int j = 0; j < 32; j++) s += Aw[j * 33 + tid] * uu[j];
        vv[tid] = s;
      }
      __syncthreads();
      if (tid == 0) {
        float n = 0;
        for (int j = 0; j < 32; j++) n += vv[j] * vv[j];
        red[0] = sqrtf(n);
      }
      __syncthreads();
      float nv = fmaxf(red[0], 1e-30f);
      if (tid < 32) vv[tid] /= nv;
      __syncthreads();
    }
    sigma = red[0];
  }
  float gamma_c = fminf(expf(lgamma[0]), 1.0f);
  float scale = gamma_c / fmaxf(fmaxf(sigma, 1e-8f), 1.0f);

  for (int e = tid; e < 1024; e += 256) {
    int i = e >> 5, c = e & 31;
    float s = 0;
#pragma unroll
    for (int k = 0; k < 32; k++) s += Ms[i * 32 + k] * Gi[k * 32 + c];
    Nn[e] = scale * s;
  }
  __syncthreads();
  for (int e = tid; e < 1024; e += 256) {
    int i = e >> 5, c = e & 31;
    float s = 0;
#pragma unroll
    for (int k = 0; k < 32; k++) s += Nn[i * 32 + k] * Nn[k * 32 + c];
    N2[e] = s;
  }
  __syncthreads();
  for (int e = tid; e < 1024; e += 256) {
    int i = e >> 5, c = e & 31;
    float s = 0;
#pragma unroll
    for (int k = 0; k < 32; k++) s += N2[i * 32 + k] * N2[k * 32 + c];
    Ms[e] = s;
  }
  __syncthreads();
  for (int e = tid; e < 1024; e += 256) {
    int i = e >> 5, c = e & 31;
    float s = 0;
#pragma unroll
    for (int k = 0; k < 32; k++) s += Gi[i * 32 + k] * Ms[k * 32 + c];
    T1[e] = s;
  }
  __syncthreads();
  for (int e = tid; e < 2048; e += 256) {
    int j = e >> 6, d = e & 63;
    float s = 0;
#pragma unroll
    for (int k = 0; k < 32; k++) s += Cs[d * 32 + k] * T1[k * 32 + j];
    Ft[(size_t)bh * 2048 + e] = s;
  }
}

// ------- E-build: Et[b][n][h*32+j] = sg * sum_d F[d,j] * Wo[h*64+d, n], split hi/lo -------
__global__ __launch_bounds__(256) void e_k(const float* __restrict__ Ft,
                                           const float* __restrict__ Wo,
                                           const float* __restrict__ alpha,
                                           unsigned short* __restrict__ ETH,
                                           unsigned short* __restrict__ ETL) {
  const int n0 = blockIdx.x * 256, h = blockIdx.y, b = blockIdx.z;
  const int bh = b * NH + h;
  const int tid = threadIdx.x;
  __shared__ float F[2048];
  __shared__ float eb[256][33];
  for (int e = tid; e < 2048; e += 256) F[e] = Ft[(size_t)bh * 2048 + e];
  __syncthreads();
  const float sg = 1.0f / (1.0f + expf(-alpha[0]));
  const int n = n0 + tid;
  float acc[32];
#pragma unroll
  for (int j = 0; j < 32; j++) acc[j] = 0.f;
  for (int d = 0; d < 64; d++) {
    float wv = Wo[(size_t)(h * 64 + d) * 1024 + n];
#pragma unroll
    for (int j = 0; j < 32; j++) acc[j] += F[j * 64 + d] * wv;
  }
#pragma unroll
  for (int j = 0; j < 32; j++) eb[tid][j] = sg * acc[j];
  __syncthreads();
  const int jp = (tid & 3) * 8;
  for (int rr = tid >> 2; rr < 256; rr += 64) {
    unsigned short hi[8], lo[8];
#pragma unroll
    for (int i = 0; i < 8; i++) split_bf16(eb[rr][jp + i], hi[i], lo[i]);
    size_t o = ((size_t)b * 1024 + n0 + rr) * 512 + h * 32 + jp;
    *(ushort4*)&ETH[o]     = make_ushort4(hi[0], hi[1], hi[2], hi[3]);
    *(ushort4*)&ETH[o + 4] = make_ushort4(hi[4], hi[5], hi[6], hi[7]);
    *(ushort4*)&ETL[o]     = make_ushort4(lo[0], lo[1], lo[2], lo[3]);
    *(ushort4*)&ETL[o + 4] = make_ushort4(lo[4], lo[5], lo[6], lo[7]);
  }
}

// ------- final GEMM: out = Y1 @ E_b  (M=16384, K=512, N=1024; sg folded in E) -------
__global__ __launch_bounds__(256) void gemm_fin_k(
    const unsigned short* __restrict__ Y1H,
    const unsigned short* __restrict__ ETH, const unsigned short* __restrict__ ETL,
    float* __restrict__ out) {
  const int m0 = blockIdx.y * 128;
  const int n0 = blockIdx.x * 128;
  const int b = m0 >> 12;
  __shared__ __align__(16) unsigned short Ah[128 * 32], Bh[128 * 32], Bl[128 * 32];
  const int tid = threadIdx.x, lane = tid & 63, w = tid >> 6;
  const int wm = (w >> 1) * 64, wn = (w & 1) * 64;
  const int lm = lane & 15, lq = lane >> 4;
  const unsigned short* Arow  = &Y1H[(size_t)m0 * 512];
  const unsigned short* BHrow = &ETH[((size_t)b * 1024 + n0) * 512];
  const unsigned short* BLrow = &ETL[((size_t)b * 1024 + n0) * 512];
  f4v acc[4][4];
#pragma unroll
  for (int i = 0; i < 4; i++)
#pragma unroll
    for (int j = 0; j < 4; j++) acc[i][j] = (f4v){0.f, 0.f, 0.f, 0.f};

  for (int kt = 0; kt < 512; kt += 32) {
    __syncthreads();
#pragma unroll
    for (int i = 0; i < 2; i++) {
      int sbase = w * 128 + i * 64;
      int idx = sbase + lane;
      int r = idx >> 2, cl = idx & 3;
      int cg = cl ^ ((r + (r >> 2)) & 3);
      size_t go = (size_t)r * 512 + kt + cg * 8;
      GLOAD(&Arow[go],  &Ah[sbase * 8]);
      GLOAD(&BHrow[go], &Bh[sbase * 8]);
      GLOAD(&BLrow[go], &Bl[sbase * 8]);
    }
    __syncthreads();
    s8v ah[4], bh4[4], bl4[4];
#pragma unroll
    for (int i = 0; i < 4; i++) {
      int arr = wm + i * 16 + lm;
      int ach = lq ^ ((arr + (arr >> 2)) & 3);
      ah[i] = *(const s8v*)&Ah[arr * 32 + ach * 8];
      int brr = wn + i * 16 + lm;
      int bch = lq ^ ((brr + (brr >> 2)) & 3);
      bh4[i] = *(const s8v*)&Bh[brr * 32 + bch * 8];
      bl4[i] = *(const s8v*)&Bl[brr * 32 + bch * 8];
    }
#pragma unroll
    for (int mi = 0; mi < 4; mi++)
#pragma unroll
      for (int ni = 0; ni < 4; ni++) {
        acc[mi][ni] = __builtin_amdgcn_mfma_f32_16x16x32_bf16(ah[mi], bh4[ni], acc[mi][ni], 0, 0, 0);
        acc[mi][ni] = __builtin_amdgcn_mfma_f32_16x16x32_bf16(ah[mi], bl4[ni], acc[mi][ni], 0, 0, 0);
      }
  }
#pragma unroll
  for (int mi = 0; mi < 4; mi++)
#pragma unroll
    for (int r = 0; r < 4; r++) {
      size_t orow = (size_t)(m0 + wm + mi * 16 + lq * 4 + r);
#pragma unroll
      for (int ni = 0; ni < 4; ni++)
        out[orow * 1024 + n0 + wn + ni * 16 + lm] = acc[mi][ni][r];
    }
}

extern "C" void kernel_launch(void* const* d_in, const int* in_sizes, int n_in,
                              void* d_out, int out_size, void* d_ws, size_t ws_size,
                              hipStream_t stream) {
  const float* X      = (const float*)d_in[0];
  const float* Wk     = (const float*)d_in[1];
  const float* Wq     = (const float*)d_in[2];
  const float* Wv     = (const float*)d_in[3];
  const float* Wo     = (const float*)d_in[4];
  const float* lng    = (const float*)d_in[5];
  const float* lnb    = (const float*)d_in[6];
  const float* alpha  = (const float*)d_in[7];
  const float* lridge = (const float*)d_in[8];
  const float* lgamma = (const float*)d_in[9];
  const int*   pref   = (const int*)d_in[10];
  float* out = (float*)d_out;
  char* ws = (char*)d_ws;
  float* stats = (float*)(ws + OFF_STATS);
  float* G     = (float*)(ws + OFF_G);
  float* Mm    = (float*)(ws + OFF_MM);
  float* Cv    = (float*)(ws + OFF_CV);
  float* Ft    = (float*)(ws + OFF_FT);
  float* AFF   = (float*)(ws + OFF_AFF);
  unsigned short* WKVH = (unsigned short*)(ws + OFF_WKVH);
  unsigned short* WKVL = (unsigned short*)(ws + OFF_WKVL);
  unsigned short* WQH  = (unsigned short*)(ws + OFF_WQH);
  unsigned short* WQL  = (unsigned short*)(ws + OFF_WQL);
  unsigned short* ETH  = (unsigned short*)(ws + OFF_ETH);
  unsigned short* ETL  = (unsigned short*)(ws + OFF_ETL);
  float* Y1F = (float*)(ws + OFF_Y1F);
  unsigned short* Y1H = (unsigned short*)(ws + OFF_Y1H);
  float* Y2  = (float*)(ws + OFF_Y2);

  hipMemsetAsync(ws + OFF_G, 0, 1 << 20, stream);
  ln_stats_k<<<16384, 256, 0, stream>>>(X, stats);
  prep_w_k<<<dim3(16, 32), 256, 0, stream>>>(Wk, 512, 0, lng, WKVH, WKVL);
  prep_w_k<<<dim3(32, 32), 256, 0, stream>>>(Wv, 1024, 512, lng, WKVH, WKVL);
  prep_w_k<<<dim3(16, 32), 256, 0, stream>>>(Wq, 512, 0, lng, WQH, WQL);
  affine_k<<<2, 256, 0, stream>>>(Wk, 512, lng, lnb, AFF, AFF + 1536);
  affine_k<<<4, 256, 0, stream>>>(Wv, 1024, lng, lnb, AFF + 512, AFF + 1536 + 512);
  affine_k<<<2, 256, 0, stream>>>(Wq, 512, lng, lnb, AFF + 3072, AFF + 3584);
  gemm_proj_k<<<dim3(12, 128), 256, 0, stream>>>(X, stats, WKVH, WKVL, AFF, AFF + 1536,
                                                 pref, 0, Y1F, Y1H, Y2);
  gemm_proj_k<<<dim3(4, 128), 256, 0, stream>>>(X, stats, WQH, WQL, AFF + 3072, AFF + 3584,
                                                pref, 1, Y1F, Y1H, Y2);
  build_gmc_k<<<dim3(NCH, 64), 256, 0, stream>>>(Y1F, Y2, pref, G, Mm, Cv);
  solve_op_k<<<64, 256, 0, stream>>>(G, Mm, Cv, lridge, lgamma, Ft);
  e_k<<<dim3(4, NH, NB), 256, 0, stream>>>(Ft, Wo, alpha, ETH, ETL);
  gemm_fin_k<<<dim3(8, 128), 256, 0, stream>>>(Y1H, ETH, ETL, out);
}

// Round 4
// 661.529 us; speedup vs baseline: 1.1716x; 1.1716x over previous
//
#include <hip/hip_runtime.h>
#include <math.h>

#define D_MODEL 1024
#define TT 4096
#define NB 4
#define NH 16
#define NCH 16

typedef __attribute__((ext_vector_type(8))) short s8v;
typedef __attribute__((ext_vector_type(4))) float f4v;

// ---- workspace layout (bytes); same proven footprint as R3 (~102 MB @ P=2048) ----
#define OFF_STATS ((size_t)0)
#define OFF_G     ((size_t)(1 << 20))
#define OFF_MM    (OFF_G + (size_t)(256 << 10))
#define OFF_CV    (OFF_MM + (size_t)(256 << 10))
#define OFF_FT    ((size_t)(2 << 20))
#define OFF_AFF   (OFF_FT + (size_t)(512 << 10))
#define OFF_WKVH  ((size_t)(3 << 20))
#define OFF_WKVL  ((size_t)(6 << 20))
#define OFF_WQH   ((size_t)(9 << 20))
#define OFF_WQL   ((size_t)(10 << 20))
#define OFF_ETH   ((size_t)(11 << 20))
#define OFF_ETL   ((size_t)(15 << 20))
#define OFF_Y1F   ((size_t)(20 << 20))
#define OFF_Y1H   ((size_t)(52 << 20))
#define OFF_Y2    ((size_t)(68 << 20))

#define GLOAD(g, l) __builtin_amdgcn_global_load_lds(                         \
    (const __attribute__((address_space(1))) unsigned int*)(const void*)(g),  \
    (__attribute__((address_space(3))) unsigned int*)(void*)(l), 16, 0, 0)

__device__ __forceinline__ unsigned short bf16_rne(float x) {
  unsigned u = __float_as_uint(x);
  return (unsigned short)((u + 0x7fffu + ((u >> 16) & 1u)) >> 16);
}
// hi = truncation (exact residual goes to lo): ~half the VALU of double-RNE,
// identical pair accuracy (hi+lo error = lo's own RNE, ~2^-17 rel)
__device__ __forceinline__ void split_trunc(float x, unsigned short& h, unsigned short& l) {
  unsigned u = __float_as_uint(x);
  h = (unsigned short)(u >> 16);
  l = bf16_rne(x - __uint_as_float(u & 0xffff0000u));
}
__device__ __forceinline__ void split_bf16(float x, unsigned short& h, unsigned short& l) {
  unsigned u = __float_as_uint(x);
  unsigned r = (u + 0x7fffu + ((u >> 16) & 1u)) & 0xffff0000u;
  h = (unsigned short)(r >> 16);
  l = bf16_rne(x - __uint_as_float(r));
}

// ---------------- LayerNorm statistics: one block per row ----------------
__global__ __launch_bounds__(256) void ln_stats_k(const float* __restrict__ X,
                                                  float* __restrict__ stats) {
  int r = blockIdx.x;
  const float4 v = ((const float4*)(X + (size_t)r * D_MODEL))[threadIdx.x];
  float s  = v.x + v.y + v.z + v.w;
  float ss = v.x * v.x + v.y * v.y + v.z * v.z + v.w * v.w;
#pragma unroll
  for (int off = 32; off > 0; off >>= 1) {
    s  += __shfl_down(s, off, 64);
    ss += __shfl_down(ss, off, 64);
  }
  __shared__ float as_[4], bs_[4];
  int w = threadIdx.x >> 6, lane = threadIdx.x & 63;
  if (lane == 0) { as_[w] = s; bs_[w] = ss; }
  __syncthreads();
  if (threadIdx.x == 0) {
    float S  = as_[0] + as_[1] + as_[2] + as_[3];
    float SS = bs_[0] + bs_[1] + bs_[2] + bs_[3];
    float mu  = S * (1.0f / D_MODEL);
    float var = SS * (1.0f / D_MODEL) - mu * mu;
    stats[2 * (size_t)r]     = mu;
    stats[2 * (size_t)r + 1] = 1.0f / sqrtf(var + 1e-5f);
  }
}

// ------- prep: transpose (diag(g)·W) -> [nofs+n][K] bf16 hi/lo + affine partials -------
// affG[nofs+n] += sum_k g[k]W[k,n]; affB[nofs+n] += sum_k b[k]W[k,n]  (atomic)
__global__ __launch_bounds__(256) void prep_w_k(const float* __restrict__ W, int N, int nofs,
                                                const float* __restrict__ g,
                                                const float* __restrict__ bvec,
                                                unsigned short* __restrict__ Thi,
                                                unsigned short* __restrict__ Tlo,
                                                float* __restrict__ affG,
                                                float* __restrict__ affB) {
  __shared__ float tileT[32 * 33];
  __shared__ float rawT[32 * 33];
  const int n0 = blockIdx.x * 32, k0 = blockIdx.y * 32;
  const int tid = threadIdx.x;
  {
    int k_l = tid >> 3, n4 = (tid & 7) << 2;
    float gk = g[k0 + k_l];
    float4 v = *(const float4*)&W[(size_t)(k0 + k_l) * N + n0 + n4];
    rawT[(n4 + 0) * 33 + k_l] = v.x;  tileT[(n4 + 0) * 33 + k_l] = v.x * gk;
    rawT[(n4 + 1) * 33 + k_l] = v.y;  tileT[(n4 + 1) * 33 + k_l] = v.y * gk;
    rawT[(n4 + 2) * 33 + k_l] = v.z;  tileT[(n4 + 2) * 33 + k_l] = v.z * gk;
    rawT[(n4 + 3) * 33 + k_l] = v.w;  tileT[(n4 + 3) * 33 + k_l] = v.w * gk;
  }
  __syncthreads();
  {
    int n_l = tid >> 3, k4 = (tid & 7) << 2;
    unsigned short h[4], l[4];
    float pg = 0.f, pb = 0.f;
#pragma unroll
    for (int i = 0; i < 4; i++) {
      float tv = tileT[n_l * 33 + k4 + i];
      split_bf16(tv, h[i], l[i]);
      pg += tv;
      pb += bvec[k0 + k4 + i] * rawT[n_l * 33 + k4 + i];
    }
    *(ushort4*)&Thi[(size_t)(nofs + n0 + n_l) * 1024 + k0 + k4] = make_ushort4(h[0], h[1], h[2], h[3]);
    *(ushort4*)&Tlo[(size_t)(nofs + n0 + n_l) * 1024 + k0 + k4] = make_ushort4(l[0], l[1], l[2], l[3]);
    pg += __shfl_down(pg, 4, 8); pg += __shfl_down(pg, 2, 8); pg += __shfl_down(pg, 1, 8);
    pb += __shfl_down(pb, 4, 8); pb += __shfl_down(pb, 2, 8); pb += __shfl_down(pb, 1, 8);
    if ((tid & 7) == 0) {
      atomicAdd(&affG[nofs + n0 + n_l], pg);
      atomicAdd(&affB[nofs + n0 + n_l], pb);
    }
  }
}

// ------- projection GEMM: raw-X split-bf16 (3 products), LN folded to epilogue -------
// mode 0 (BN=256): rows t<P compact, W=[WgK|WgV] N=1536; n<512 -> keys, else values
// mode 1 (BN=128): rows t>=P compact, W=WgQ N=512 -> queries
template <int BN>
__global__ __launch_bounds__(256) void gemm_proj_k(
    const float* __restrict__ X, const float* __restrict__ stats,
    const unsigned short* __restrict__ WTh, const unsigned short* __restrict__ WTl,
    const float* __restrict__ affG, const float* __restrict__ affB,
    const int* __restrict__ pref, int mode,
    float* __restrict__ Y1F, unsigned short* __restrict__ Y1H,
    float* __restrict__ Y2) {
  int P = pref[0]; P = P < 1 ? 1 : (P > TT - 1 ? TT - 1 : P);
  const int limit = (mode == 0) ? NB * P : NB * (TT - P);
  const int m0 = blockIdx.y * 128;
  if (m0 >= limit) return;
  const int n0 = blockIdx.x * BN;
  constexpr int NI = BN / 32;           // b-frag count per wave (wave covers BN/2 cols)
  __shared__ __align__(16) unsigned short Ah[128 * 32], Al[128 * 32];
  __shared__ __align__(16) unsigned short Bh[BN * 32], Bl[BN * 32];
  __shared__ int rowoff[128];
  __shared__ float mus[128], rss[128];
  __shared__ float aGs[BN], aBs[BN];
  const int tid = threadIdx.x;
  if (tid < 128) {
    int gm = m0 + tid;
    int grow = 0;
    if (gm < limit) {
      if (mode == 0) {
        unsigned bq = (unsigned)gm / (unsigned)P;
        grow = bq * TT + (gm - bq * P);
      } else {
        unsigned q = (unsigned)(TT - P);
        unsigned bq = (unsigned)gm / q;
        grow = bq * TT + P + (gm - bq * q);
      }
    }
    rowoff[tid] = grow;
    mus[tid] = stats[2 * (size_t)grow];
    rss[tid] = stats[2 * (size_t)grow + 1];
  }
  for (int e = tid; e < BN; e += 256) {
    aGs[e] = affG[n0 + e];
    aBs[e] = affB[n0 + e];
  }
  const int lane = tid & 63;
  const int w = tid >> 6;
  const int wm = (w >> 1) * 64, wn = (w & 1) * (BN / 2);
  const int lm = lane & 15, lq = lane >> 4;
  f4v acc[4][NI];
#pragma unroll
  for (int i = 0; i < 4; i++)
#pragma unroll
    for (int j = 0; j < NI; j++) acc[i][j] = (f4v){0.f, 0.f, 0.f, 0.f};

  for (int kt = 0; kt < 1024; kt += 32) {
    __syncthreads();
    // B: async global->LDS, XOR-swizzled chunks (unpadded stride 32)
#pragma unroll
    for (int i = 0; i < BN / 64; i++) {
      int id = i * 256 + tid;
      int r = id >> 2, cl = id & 3;
      int cg = cl ^ ((r + (r >> 2)) & 3);
      size_t go = (size_t)(n0 + r) * 1024 + kt + cg * 8;
      int sb = (i * 256 + (tid & 192)) * 8;
      GLOAD(&WTh[go], &Bh[sb]);
      GLOAD(&WTl[go], &Bl[sb]);
    }
    // A: fp32 load + trunc-split into XOR-swizzled LDS (stride 32)
#pragma unroll
    for (int q = 0; q < 2; q++) {
      int c = tid * 2 + q;
      int m = c >> 2, k8 = (c & 3) << 3, c8 = c & 3;
      const float* src = &X[(size_t)rowoff[m] * 1024 + kt + k8];
      float4 v0 = *(const float4*)&src[0];
      float4 v1 = *(const float4*)&src[4];
      float vv[8] = {v0.x, v0.y, v0.z, v0.w, v1.x, v1.y, v1.z, v1.w};
      unsigned short hh[8], ll[8];
#pragma unroll
      for (int i = 0; i < 8; i++) split_trunc(vv[i], hh[i], ll[i]);
      int sw = m * 32 + (c8 ^ ((m + (m >> 2)) & 3)) * 8;
      *(ushort4*)&Ah[sw]     = make_ushort4(hh[0], hh[1], hh[2], hh[3]);
      *(ushort4*)&Ah[sw + 4] = make_ushort4(hh[4], hh[5], hh[6], hh[7]);
      *(ushort4*)&Al[sw]     = make_ushort4(ll[0], ll[1], ll[2], ll[3]);
      *(ushort4*)&Al[sw + 4] = make_ushort4(ll[4], ll[5], ll[6], ll[7]);
    }
    __syncthreads();
    s8v ah[4], al[4];
#pragma unroll
    for (int i = 0; i < 4; i++) {
      int rr = wm + i * 16 + lm;
      int ao = rr * 32 + ((lq ^ ((rr + (rr >> 2)) & 3)) * 8);
      ah[i] = *(const s8v*)&Ah[ao];
      al[i] = *(const s8v*)&Al[ao];
    }
#pragma unroll
    for (int ni = 0; ni < NI; ni++) {
      int brr = wn + ni * 16 + lm;
      int bo = brr * 32 + ((lq ^ ((brr + (brr >> 2)) & 3)) * 8);
      s8v bh4 = *(const s8v*)&Bh[bo];
      s8v bl4 = *(const s8v*)&Bl[bo];
#pragma unroll
      for (int mi = 0; mi < 4; mi++) {
        acc[mi][ni] = __builtin_amdgcn_mfma_f32_16x16x32_bf16(ah[mi], bh4, acc[mi][ni], 0, 0, 0);
        acc[mi][ni] = __builtin_amdgcn_mfma_f32_16x16x32_bf16(ah[mi], bl4, acc[mi][ni], 0, 0, 0);
        acc[mi][ni] = __builtin_amdgcn_mfma_f32_16x16x32_bf16(al[mi], bh4, acc[mi][ni], 0, 0, 0);
      }
    }
  }
#pragma unroll
  for (int mi = 0; mi < 4; mi++) {
#pragma unroll
    for (int r = 0; r < 4; r++) {
      int ml = wm + mi * 16 + lq * 4 + r;
      int gm = m0 + ml;
      if (gm >= limit) continue;
      int grow = rowoff[ml];
      float mu = mus[ml], rs = rss[ml];
#pragma unroll
      for (int ni = 0; ni < NI; ni++) {
        int nl = wn + ni * 16 + lm;
        int n = n0 + nl;
        float v = rs * acc[mi][ni][r] + aBs[nl] - rs * mu * aGs[nl];
        if (mode == 0) {
          if (n < 512) {
            Y1F[(size_t)grow * 512 + n] = v;
            Y1H[(size_t)grow * 512 + n] = bf16_rne(v);
          } else {
            Y2[(size_t)gm * 1024 + (n - 512)] = v;
          }
        } else {
          Y1H[(size_t)grow * 512 + n] = bf16_rne(v);
        }
      }
    }
  }
}

// ------------- G, M, C_v Gram reductions (atomic accumulate) -------------
__global__ __launch_bounds__(256) void build_gmc_k(
    const float* __restrict__ Y1, const float* __restrict__ Y2,
    const int* __restrict__ pref,
    float* __restrict__ G, float* __restrict__ Mm, float* __restrict__ Cv) {
  int P = pref[0]; P = P < 1 ? 1 : (P > TT - 1 ? TT - 1 : P);
  const int bh = blockIdx.y;
  const int b = bh >> 4, h = bh & 15;
  const int tid = threadIdx.x;
  const int chunk = (P + NCH - 1) / NCH;
  const int tb = blockIdx.x * chunk;
  const int te = min(tb + chunk, P);
  if (tb >= te) return;
  __shared__ float kt[129 * 32];
  __shared__ float vt[128 * 64];
  float aG[4] = {}, aM[4] = {}, aC[8] = {};
  const int ii = tid >> 3, j4 = (tid & 7) << 2;
  const int dd = tid >> 2, j8 = (tid & 3) << 3;
  for (int t0 = tb; t0 < te; t0 += 128) {
    const int len = min(128, te - t0);
    __syncthreads();
    for (int e = tid; e < (len + 1) * 8; e += 256) {
      int row = e >> 3, jj = (e & 7) << 2;
      int t = t0 - 1 + row;
      float4 v = make_float4(0.f, 0.f, 0.f, 0.f);
      if (t >= 0) v = *(const float4*)&Y1[((size_t)b * TT + t) * 512 + h * 32 + jj];
      *(float4*)&kt[row * 32 + jj] = v;
    }
    for (int e = tid; e < len * 16; e += 256) {
      int row = e >> 4, dj = (e & 15) << 2;
      int t = t0 + row;
      *(float4*)&vt[row * 64 + dj] =
          *(const float4*)&Y2[((size_t)b * P + t) * 1024 + h * 64 + dj];
    }
    __syncthreads();
    for (int s = 0; s < len; s++) {
      float ki  = kt[(s + 1) * 32 + ii];
      float4 kj = *(const float4*)&kt[(s + 1) * 32 + j4];
      float4 km = *(const float4*)&kt[s * 32 + j4];
      aG[0] += ki * kj.x; aG[1] += ki * kj.y; aG[2] += ki * kj.z; aG[3] += ki * kj.w;
      aM[0] += ki * km.x; aM[1] += ki * km.y; aM[2] += ki * km.z; aM[3] += ki * km.w;
      float vd  = vt[s * 64 + dd];
      float4 ka = *(const float4*)&kt[(s + 1) * 32 + j8];
      float4 kb = *(const float4*)&kt[(s + 1) * 32 + j8 + 4];
      aC[0] += vd * ka.x; aC[1] += vd * ka.y; aC[2] += vd * ka.z; aC[3] += vd * ka.w;
      aC[4] += vd * kb.x; aC[5] += vd * kb.y; aC[6] += vd * kb.z; aC[7] += vd * kb.w;
    }
  }
  float* Gd = &G[(size_t)bh * 1024 + ii * 32 + j4];
  atomicAdd(&Gd[0], aG[0]); atomicAdd(&Gd[1], aG[1]);
  atomicAdd(&Gd[2], aG[2]); atomicAdd(&Gd[3], aG[3]);
  float* Md = &Mm[(size_t)bh * 1024 + ii * 32 + j4];
  atomicAdd(&Md[0], aM[0]); atomicAdd(&Md[1], aM[1]);
  atomicAdd(&Md[2], aM[2]); atomicAdd(&Md[3], aM[3]);
  float* Cd = &Cv[(size_t)bh * 2048 + dd * 32 + j8];
#pragma unroll
  for (int q = 0; q < 8; q++) atomicAdd(&Cd[q], aC[q]);
}

// ------- per-(b,h) operator: chol, G^{-1}, A_w, sigma, F = Cv*Gi*(s*M*Gi)^4 -------
__global__ __launch_bounds__(256) void solve_op_k(
    const float* __restrict__ G, const float* __restrict__ Mm,
    const float* __restrict__ Cv, const float* __restrict__ lridge,
    const float* __restrict__ lgamma, float* __restrict__ Ft) {
  __shared__ float Gs[32 * 33];
  __shared__ float Ms[32 * 32];
  __shared__ float Gi[32 * 32];
  __shared__ float W1[32 * 33];
  __shared__ float Aw[32 * 33];
  __shared__ float Nn[32 * 32];
  __shared__ float N2[32 * 32];
  __shared__ float T1[32 * 32];
  __shared__ float Cs[64 * 32];
  __shared__ float red[256];
  __shared__ float vv[32], uu[32];
  const int bh = blockIdx.x;
  const int tid = threadIdx.x;
  const float ridge = expf(lridge[0]);

  for (int e = tid; e < 1024; e += 256) {
    int i = e >> 5, j = e & 31;
    float g = G[(size_t)bh * 1024 + e];
    if (i == j) g += ridge;
    Gs[i * 33 + j] = g;
    Ms[e] = Mm[(size_t)bh * 1024 + e];
  }
  for (int e = tid; e < 2048; e += 256) Cs[e] = Cv[(size_t)bh * 2048 + e];
  __syncthreads();

  for (int j = 0; j < 32; j++) {
    float d = Gs[j * 33 + j];
    __syncthreads();
    float inv = 1.0f / sqrtf(d);
    if (tid >= j && tid < 32) Gs[tid * 33 + j] *= inv;
    __syncthreads();
    int w = 31 - j;
    for (int e = tid; e < w * w; e += 256) {
      int i = j + 1 + e / w, k = j + 1 + e % w;
      Gs[i * 33 + k] -= Gs[i * 33 + j] * Gs[k * 33 + j];
    }
    __syncthreads();
  }

  if (tid < 32) {
    const int c = tid;
    for (int i = 0; i < 32; i++) W1[i * 33 + c] = (i == c) ? 1.0f : 0.0f;
    for (int i = 0; i < 32; i++) {
      float s = W1[i * 33 + c];
      for (int j = 0; j < i; j++) s -= Gs[i * 33 + j] * W1[j * 33 + c];
      W1[i * 33 + c] = s / Gs[i * 33 + i];
    }
    for (int i = 31; i >= 0; i--) {
      float s = W1[i * 33 + c];
      for (int j = i + 1; j < 32; j++) s -= Gs[j * 33 + i] * W1[j * 33 + c];
      W1[i * 33 + c] = s / Gs[i * 33 + i];
    }
    for (int i = 0; i < 32; i++) Gi[i * 32 + c] = W1[i * 33 + c];
  }
  __syncthreads();
  if (tid < 32) {
    const int c = tid;
    for (int i = 0; i < 32; i++) {
      float s = Ms[i * 32 + c];
      for (int j = 0; j < i; j++) s -= Gs[i * 33 + j] * W1[j * 33 + c];
      W1[i * 33 + c] = s / Gs[i * 33 + i];
    }
  }
  __syncthreads();
  if (tid < 32) {
    const int c = tid;
    for (int i = 0; i < 32; i++) {
      float s = W1[c * 33 + i];
      for (int j = 0; j < i; j++) s -= Gs[i * 33 + j] * Aw[j * 33 + c];
      Aw[i * 33 + c] = s / Gs[i * 33 + i];
    }
  }
  __syncthreads();

  float s0 = 0.0f;
  for (int e = tid; e < 1024; e += 256) {
    float a = Aw[(e >> 5) * 33 + (e & 31)];
    s0 += a * a;
  }
  red[tid] = s0;
  __syncthreads();
  for (int off = 128; off > 0; off >>= 1) {
    if (tid < off) red[tid] += red[tid + off];
    __syncthreads();
  }
  float frob2 = red[0];
  float sigma;
  if (frob2 <= 1.0f) {
    sigma = sqrtf(frob2);
  } else {
    if (tid < 32) vv[tid] = 1.0f + 0.001f * (float)tid;
    __syncthreads();
    for (int it = 0; it < 64; it++) {
      if (tid < 32) {
        float s = 0;
        for (int j = 0; j < 32; j++) s += Aw[tid * 33 + j] * vv[j];
        uu[tid] = s;
      }
      __syncthreads();
      if (tid == 0) {
        float n = 0;
        for (int j = 0; j < 32; j++) n += uu[j] * uu[j];
        red[0] = sqrtf(n);
      }
      __syncthreads();
      float nu = fmaxf(red[0], 1e-30f);
      if (tid < 32) uu[tid] /= nu;
      __syncthreads();
      if (tid < 32) {
        float s = 0;
        for (int j = 0; j < 32; j++) s += Aw[j * 33 + tid] * uu[j];
        vv[tid] = s;
      }
      __syncthreads();
      if (tid == 0) {
        float n = 0;
        for (int j = 0; j < 32; j++) n += vv[j] * vv[j];
        red[0] = sqrtf(n);
      }
      __syncthreads();
      float nv = fmaxf(red[0], 1e-30f);
      if (tid < 32) vv[tid] /= nv;
      __syncthreads();
    }
    sigma = red[0];
  }
  float gamma_c = fminf(expf(lgamma[0]), 1.0f);
  float scale = gamma_c / fmaxf(fmaxf(sigma, 1e-8f), 1.0f);

  for (int e = tid; e < 1024; e += 256) {
    int i = e >> 5, c = e & 31;
    float s = 0;
#pragma unroll
    for (int k = 0; k < 32; k++) s += Ms[i * 32 + k] * Gi[k * 32 + c];
    Nn[e] = scale * s;
  }
  __syncthreads();
  for (int e = tid; e < 1024; e += 256) {
    int i = e >> 5, c = e & 31;
    float s = 0;
#pragma unroll
    for (int k = 0; k < 32; k++) s += Nn[i * 32 + k] * Nn[k * 32 + c];
    N2[e] = s;
  }
  __syncthreads();
  for (int e = tid; e < 1024; e += 256) {
    int i = e >> 5, c = e & 31;
    float s = 0;
#pragma unroll
    for (int k = 0; k < 32; k++) s += N2[i * 32 + k] * N2[k * 32 + c];
    Ms[e] = s;
  }
  __syncthreads();
  for (int e = tid; e < 1024; e += 256) {
    int i = e >> 5, c = e & 31;
    float s = 0;
#pragma unroll
    for (int k = 0; k < 32; k++) s += Gi[i * 32 + k] * Ms[k * 32 + c];
    T1[e] = s;
  }
  __syncthreads();
  for (int e = tid; e < 2048; e += 256) {
    int j = e >> 6, d = e & 63;
    float s = 0;
#pragma unroll
    for (int k = 0; k < 32; k++) s += Cs[d * 32 + k] * T1[k * 32 + j];
    Ft[(size_t)bh * 2048 + e] = s;
  }
}

// ------- E-build: Et[b][n][h*32+j] = sg * sum_d F[d,j] * Wo[h*64+d, n], split hi/lo -------
__global__ __launch_bounds__(256) void e_k(const float* __restrict__ Ft,
                                           const float* __restrict__ Wo,
                                           const float* __restrict__ alpha,
                                           unsigned short* __restrict__ ETH,
                                           unsigned short* __restrict__ ETL) {
  const int n0 = blockIdx.x * 256, h = blockIdx.y, b = blockIdx.z;
  const int bh = b * NH + h;
  const int tid = threadIdx.x;
  __shared__ float F[2048];
  __shared__ float eb[256][33];
  for (int e = tid; e < 2048; e += 256) F[e] = Ft[(size_t)bh * 2048 + e];
  __syncthreads();
  const float sg = 1.0f / (1.0f + expf(-alpha[0]));
  const int n = n0 + tid;
  float acc[32];
#pragma unroll
  for (int j = 0; j < 32; j++) acc[j] = 0.f;
  for (int d = 0; d < 64; d++) {
    float wv = Wo[(size_t)(h * 64 + d) * 1024 + n];
#pragma unroll
    for (int j = 0; j < 32; j++) acc[j] += F[j * 64 + d] * wv;
  }
#pragma unroll
  for (int j = 0; j < 32; j++) eb[tid][j] = sg * acc[j];
  __syncthreads();
  const int jp = (tid & 3) * 8;
  for (int rr = tid >> 2; rr < 256; rr += 64) {
    unsigned short hi[8], lo[8];
#pragma unroll
    for (int i = 0; i < 8; i++) split_bf16(eb[rr][jp + i], hi[i], lo[i]);
    size_t o = ((size_t)b * 1024 + n0 + rr) * 512 + h * 32 + jp;
    *(ushort4*)&ETH[o]     = make_ushort4(hi[0], hi[1], hi[2], hi[3]);
    *(ushort4*)&ETH[o + 4] = make_ushort4(hi[4], hi[5], hi[6], hi[7]);
    *(ushort4*)&ETL[o]     = make_ushort4(lo[0], lo[1], lo[2], lo[3]);
    *(ushort4*)&ETL[o + 4] = make_ushort4(lo[4], lo[5], lo[6], lo[7]);
  }
}

// ------- final GEMM: out = Y1 @ E_b  (M=16384, K=512, N=1024; sg folded in E) -------
__global__ __launch_bounds__(256) void gemm_fin_k(
    const unsigned short* __restrict__ Y1H,
    const unsigned short* __restrict__ ETH, const unsigned short* __restrict__ ETL,
    float* __restrict__ out) {
  const int m0 = blockIdx.y * 128;
  const int n0 = blockIdx.x * 128;
  const int b = m0 >> 12;
  __shared__ __align__(16) unsigned short Ah[128 * 32], Bh[128 * 32], Bl[128 * 32];
  const int tid = threadIdx.x, lane = tid & 63, w = tid >> 6;
  const int wm = (w >> 1) * 64, wn = (w & 1) * 64;
  const int lm = lane & 15, lq = lane >> 4;
  const unsigned short* Arow  = &Y1H[(size_t)m0 * 512];
  const unsigned short* BHrow = &ETH[((size_t)b * 1024 + n0) * 512];
  const unsigned short* BLrow = &ETL[((size_t)b * 1024 + n0) * 512];
  f4v acc[4][4];
#pragma unroll
  for (int i = 0; i < 4; i++)
#pragma unroll
    for (int j = 0; j < 4; j++) acc[i][j] = (f4v){0.f, 0.f, 0.f, 0.f};

  for (int kt = 0; kt < 512; kt += 32) {
    __syncthreads();
#pragma unroll
    for (int i = 0; i < 2; i++) {
      int sbase = w * 128 + i * 64;
      int idx = sbase + lane;
      int r = idx >> 2, cl = idx & 3;
      int cg = cl ^ ((r + (r >> 2)) & 3);
      size_t go = (size_t)r * 512 + kt + cg * 8;
      GLOAD(&Arow[go],  &Ah[sbase * 8]);
      GLOAD(&BHrow[go], &Bh[sbase * 8]);
      GLOAD(&BLrow[go], &Bl[sbase * 8]);
    }
    __syncthreads();
    s8v ah[4], bh4[4], bl4[4];
#pragma unroll
    for (int i = 0; i < 4; i++) {
      int arr = wm + i * 16 + lm;
      int ach = lq ^ ((arr + (arr >> 2)) & 3);
      ah[i] = *(const s8v*)&Ah[arr * 32 + ach * 8];
      int brr = wn + i * 16 + lm;
      int bch = lq ^ ((brr + (brr >> 2)) & 3);
      bh4[i] = *(const s8v*)&Bh[brr * 32 + bch * 8];
      bl4[i] = *(const s8v*)&Bl[brr * 32 + bch * 8];
    }
#pragma unroll
    for (int mi = 0; mi < 4; mi++)
#pragma unroll
      for (int ni = 0; ni < 4; ni++) {
        acc[mi][ni] = __builtin_amdgcn_mfma_f32_16x16x32_bf16(ah[mi], bh4[ni], acc[mi][ni], 0, 0, 0);
        acc[mi][ni] = __builtin_amdgcn_mfma_f32_16x16x32_bf16(ah[mi], bl4[ni], acc[mi][ni], 0, 0, 0);
      }
  }
#pragma unroll
  for (int mi = 0; mi < 4; mi++)
#pragma unroll
    for (int r = 0; r < 4; r++) {
      size_t orow = (size_t)(m0 + wm + mi * 16 + lq * 4 + r);
#pragma unroll
      for (int ni = 0; ni < 4; ni++)
        out[orow * 1024 + n0 + wn + ni * 16 + lm] = acc[mi][ni][r];
    }
}

extern "C" void kernel_launch(void* const* d_in, const int* in_sizes, int n_in,
                              void* d_out, int out_size, void* d_ws, size_t ws_size,
                              hipStream_t stream) {
  const float* X      = (const float*)d_in[0];
  const float* Wk     = (const float*)d_in[1];
  const float* Wq     = (const float*)d_in[2];
  const float* Wv     = (const float*)d_in[3];
  const float* Wo     = (const float*)d_in[4];
  const float* lng    = (const float*)d_in[5];
  const float* lnb    = (const float*)d_in[6];
  const float* alpha  = (const float*)d_in[7];
  const float* lridge = (const float*)d_in[8];
  const float* lgamma = (const float*)d_in[9];
  const int*   pref   = (const int*)d_in[10];
  float* out = (float*)d_out;
  char* ws = (char*)d_ws;
  float* stats = (float*)(ws + OFF_STATS);
  float* G     = (float*)(ws + OFF_G);
  float* Mm    = (float*)(ws + OFF_MM);
  float* Cv    = (float*)(ws + OFF_CV);
  float* Ft    = (float*)(ws + OFF_FT);
  float* AFF   = (float*)(ws + OFF_AFF);
  unsigned short* WKVH = (unsigned short*)(ws + OFF_WKVH);
  unsigned short* WKVL = (unsigned short*)(ws + OFF_WKVL);
  unsigned short* WQH  = (unsigned short*)(ws + OFF_WQH);
  unsigned short* WQL  = (unsigned short*)(ws + OFF_WQL);
  unsigned short* ETH  = (unsigned short*)(ws + OFF_ETH);
  unsigned short* ETL  = (unsigned short*)(ws + OFF_ETL);
  float* Y1F = (float*)(ws + OFF_Y1F);
  unsigned short* Y1H = (unsigned short*)(ws + OFF_Y1H);
  float* Y2  = (float*)(ws + OFF_Y2);

  hipMemsetAsync(ws + OFF_G, 0, 1 << 20, stream);
  hipMemsetAsync(ws + OFF_AFF, 0, 4096 * sizeof(float), stream);
  ln_stats_k<<<16384, 256, 0, stream>>>(X, stats);
  prep_w_k<<<dim3(16, 32), 256, 0, stream>>>(Wk, 512, 0, lng, lnb, WKVH, WKVL, AFF, AFF + 1536);
  prep_w_k<<<dim3(32, 32), 256, 0, stream>>>(Wv, 1024, 512, lng, lnb, WKVH, WKVL, AFF, AFF + 1536);
  prep_w_k<<<dim3(16, 32), 256, 0, stream>>>(Wq, 512, 0, lng, lnb, WQH, WQL, AFF + 3072, AFF + 3584);
  gemm_proj_k<256><<<dim3(6, 128), 256, 0, stream>>>(X, stats, WKVH, WKVL, AFF, AFF + 1536,
                                                     pref, 0, Y1F, Y1H, Y2);
  gemm_proj_k<128><<<dim3(4, 128), 256, 0, stream>>>(X, stats, WQH, WQL, AFF + 3072, AFF + 3584,
                                                     pref, 1, Y1F, Y1H, Y2);
  build_gmc_k<<<dim3(NCH, 64), 256, 0, stream>>>(Y1F, Y2, pref, G, Mm, Cv);
  solve_op_k<<<64, 256, 0, stream>>>(G, Mm, Cv, lridge, lgamma, Ft);
  e_k<<<dim3(4, NH, NB), 256, 0, stream>>>(Ft, Wo, alpha, ETH, ETL);
  gemm_fin_k<<<dim3(8, 128), 256, 0, stream>>>(Y1H, ETH, ETL, out);
}